// Round 1
// baseline (1672.950 us; speedup 1.0000x reference)
//
#include <hip/hip_runtime.h>

typedef __attribute__((ext_vector_type(8))) short bf16x8;
typedef __attribute__((ext_vector_type(4))) float f32x4;
typedef __attribute__((ext_vector_type(4))) int   i32x4;

// Pack 8 f32 -> 8 bf16 (truncate) via v_perm_b32: 1 inst per pair.
__device__ __forceinline__ bf16x8 pack8(f32x4 a, f32x4 b) {
  i32x4 ia = __builtin_bit_cast(i32x4, a);
  i32x4 ib = __builtin_bit_cast(i32x4, b);
  i32x4 pk;
  pk.x = (int)__builtin_amdgcn_perm((unsigned)ia.y, (unsigned)ia.x, 0x07060302u);
  pk.y = (int)__builtin_amdgcn_perm((unsigned)ia.w, (unsigned)ia.z, 0x07060302u);
  pk.z = (int)__builtin_amdgcn_perm((unsigned)ib.y, (unsigned)ib.x, 0x07060302u);
  pk.w = (int)__builtin_amdgcn_perm((unsigned)ib.w, (unsigned)ib.z, 0x07060302u);
  return __builtin_bit_cast(bf16x8, pk);
}

__device__ __forceinline__ float sigm(float v)  { return 1.0f / (1.0f + __expf(-v)); }
__device__ __forceinline__ float tanh_(float v) { return 1.0f - 2.0f / (__expf(2.0f * v) + 1.0f); }

// One workgroup = 64 nodes. 4 waves.
//   GEMM-F  : A1[64x256] (h_cat bf16)            x U_f^T   -> f_pre [64x256]
//   GEMM-IOU: A2[64x384] ([leaf?0:h | leaf?x:0]) x [U_iou|W_iou]^T -> iou_pre [64x384]
// Column-block -> wave mapping: wave = cb & 3. Then for output col j (jb=j/16):
//   f0 cb=jb, f1 cb=jb+8, i cb=jb, o cb=jb+8, u cb=jb+16  -- all in wave (jb&3),
//   same lane (j&15) -> epilogue entirely in registers.
__global__ __launch_bounds__(256, 2) void treelstm(
    const float* __restrict__ x, const float* __restrict__ h, const float* __restrict__ c,
    const int* __restrict__ children, const int* __restrict__ is_leaf,
    const float* __restrict__ W_iou, const float* __restrict__ b_Wiou,
    const float* __restrict__ U_iou, const float* __restrict__ b_Uiou,
    const float* __restrict__ U_f,  const float* __restrict__ b_Uf,
    float* __restrict__ out, int N)
{
  __shared__ short A1[64 * 256];  // 32 KB, h_cat, bf16, chunk-swizzled
  __shared__ short A2[64 * 384];  // 48 KB, [h_masked | x_masked]

  const int tid  = threadIdx.x;
  const int wave = tid >> 6;
  const int lane = tid & 63;
  const int l15  = lane & 15;
  const int quad = lane >> 4;
  const long base = (long)blockIdx.x * 64;

  // ---------------- gather / stage ----------------
  {
    const int node = tid & 63;
    const int seg  = tid >> 6;          // 0..3: (child, half-of-128)
    long gn = base + node;
    if (gn >= N) gn = 0;
    const int s  = node & 7;            // LDS chunk swizzle key
    const int lf = is_leaf[gn];
    const int ch = children[gn * 2 + (seg >> 1)];
    const float* hrow = h + (long)ch * 128 + (seg & 1) * 64;
    const int cbase = (seg >> 1) * 16 + (seg & 1) * 8;  // 16B-chunk base within row
#pragma unroll
    for (int i = 0; i < 8; ++i) {
      f32x4 v0 = *(const f32x4*)(hrow + i * 8);
      f32x4 v1 = *(const f32x4*)(hrow + i * 8 + 4);
      bf16x8 pk = pack8(v0, v1);
      const int cc = (cbase + i) ^ s;
      *(bf16x8*)&A1[node * 256 + cc * 8] = pk;
      bf16x8 pz = pk;
      if (lf) pz = bf16x8{0, 0, 0, 0, 0, 0, 0, 0};   // internal uses h, leaf -> 0
      *(bf16x8*)&A2[node * 384 + cc * 8] = pz;
    }
    const float* xrow = x + gn * 128 + seg * 32;
#pragma unroll
    for (int i = 0; i < 4; ++i) {
      f32x4 v0 = *(const f32x4*)(xrow + i * 8);
      f32x4 v1 = *(const f32x4*)(xrow + i * 8 + 4);
      bf16x8 pk = pack8(v0, v1);
      if (!lf) pk = bf16x8{0, 0, 0, 0, 0, 0, 0, 0};  // leaf uses x, internal -> 0
      const int cc = (32 + seg * 4 + i) ^ s;
      *(bf16x8*)&A2[node * 384 + cc * 8] = pk;
    }
  }
  __syncthreads();

  // ---------------- accumulators ----------------
  f32x4 accF[4][4];   // [local f col-block][row-block]
  f32x4 accI[6][4];   // [local iou col-block][row-block]
#pragma unroll
  for (int l = 0; l < 4; ++l)
#pragma unroll
    for (int rb = 0; rb < 4; ++rb) accF[l][rb] = f32x4{0, 0, 0, 0};
#pragma unroll
  for (int l = 0; l < 6; ++l)
#pragma unroll
    for (int rb = 0; rb < 4; ++rb) accI[l][rb] = f32x4{0, 0, 0, 0};

  // per-lane weight row pointers (B fragment: lane reads W[col][k..k+7])
  const float* bfp[4];
#pragma unroll
  for (int l = 0; l < 4; ++l)
    bfp[l] = U_f + (long)((wave + 4 * l) * 16 + l15) * 256 + quad * 8;
  const float* bup[6];
  const float* bwp[6];
#pragma unroll
  for (int l = 0; l < 6; ++l) {
    const int col = (wave + 4 * l) * 16 + l15;
    bup[l] = U_iou + (long)col * 256 + quad * 8;
    bwp[l] = W_iou + (long)col * 128 + quad * 8;
  }

  // ---------------- GEMM-F: K=256 over A1 ----------------
#pragma unroll
  for (int k8 = 0; k8 < 8; ++k8) {
    bf16x8 afr[4];
#pragma unroll
    for (int rb = 0; rb < 4; ++rb) {
      const int row = rb * 16 + l15;
      const int cc = (k8 * 4 + quad) ^ (row & 7);
      afr[rb] = *(const bf16x8*)&A1[row * 256 + cc * 8];
    }
#pragma unroll
    for (int l = 0; l < 4; ++l) {
      const float* p = bfp[l] + k8 * 32;
      bf16x8 b = pack8(*(const f32x4*)p, *(const f32x4*)(p + 4));
#pragma unroll
      for (int rb = 0; rb < 4; ++rb)
        accF[l][rb] = __builtin_amdgcn_mfma_f32_16x16x32_bf16(afr[rb], b, accF[l][rb], 0, 0, 0);
    }
  }

  // ---------------- GEMM-IOU part 1: k<256 (U_iou x h_masked) ----------------
#pragma unroll
  for (int k12 = 0; k12 < 8; ++k12) {
    bf16x8 afr[4];
#pragma unroll
    for (int rb = 0; rb < 4; ++rb) {
      const int row = rb * 16 + l15;
      const int cc = (k12 * 4 + quad) ^ (row & 7);
      afr[rb] = *(const bf16x8*)&A2[row * 384 + cc * 8];
    }
#pragma unroll
    for (int l = 0; l < 6; ++l) {
      const float* p = bup[l] + k12 * 32;
      bf16x8 b = pack8(*(const f32x4*)p, *(const f32x4*)(p + 4));
#pragma unroll
      for (int rb = 0; rb < 4; ++rb)
        accI[l][rb] = __builtin_amdgcn_mfma_f32_16x16x32_bf16(afr[rb], b, accI[l][rb], 0, 0, 0);
    }
  }
  // ---------------- GEMM-IOU part 2: k>=256 (W_iou x x_masked) ----------------
#pragma unroll
  for (int k4 = 0; k4 < 4; ++k4) {
    bf16x8 afr[4];
#pragma unroll
    for (int rb = 0; rb < 4; ++rb) {
      const int row = rb * 16 + l15;
      const int cc = ((8 + k4) * 4 + quad) ^ (row & 7);
      afr[rb] = *(const bf16x8*)&A2[row * 384 + cc * 8];
    }
#pragma unroll
    for (int l = 0; l < 6; ++l) {
      const float* p = bwp[l] + k4 * 32;
      bf16x8 b = pack8(*(const f32x4*)p, *(const f32x4*)(p + 4));
#pragma unroll
      for (int rb = 0; rb < 4; ++rb)
        accI[l][rb] = __builtin_amdgcn_mfma_f32_16x16x32_bf16(afr[rb], b, accI[l][rb], 0, 0, 0);
    }
  }

  // ---------------- epilogue (all in-register) ----------------
  const long NH = (long)N * 128;
#pragma unroll
  for (int g = 0; g < 2; ++g) {
    const int jb = wave + 4 * g;        // 0..7
    const int j  = jb * 16 + l15;       // output column 0..127
    const float bf0 = b_Uf[j],        bf1 = b_Uf[128 + j];
    const float bUi = b_Uiou[j],      bUo = b_Uiou[128 + j], bUu = b_Uiou[256 + j];
    const float bWi = b_Wiou[j],      bWo = b_Wiou[128 + j], bWu = b_Wiou[256 + j];
#pragma unroll
    for (int rb = 0; rb < 4; ++rb) {
#pragma unroll
      for (int ri = 0; ri < 4; ++ri) {
        const long node = base + rb * 16 + quad * 4 + ri;  // C/D row mapping
        if (node >= N) continue;
        const int ch0 = children[node * 2];
        const int ch1 = children[node * 2 + 1];
        const int lf  = is_leaf[node];
        const float c0 = c[(long)ch0 * 128 + j];
        const float c1 = c[(long)ch1 * 128 + j];
        const float f0 = sigm(accF[g][rb][ri] + bf0);
        const float f1 = sigm(accF[g + 2][rb][ri] + bf1);
        const float cf = f0 * c0 + f1 * c1;
        const float ip = accI[g][rb][ri]     + (lf ? bWi : bUi);
        const float op = accI[g + 2][rb][ri] + (lf ? bWo : bUo);
        const float up = accI[g + 4][rb][ri] + (lf ? bWu : bUu);
        const float cnew = sigm(ip) * tanh_(up) + cf;
        const float hnew = sigm(op) * tanh_(cnew);
        out[node * 128 + j]      = hnew;
        out[NH + node * 128 + j] = cnew;
      }
    }
  }
}

extern "C" void kernel_launch(void* const* d_in, const int* in_sizes, int n_in,
                              void* d_out, int out_size, void* d_ws, size_t ws_size,
                              hipStream_t stream) {
  const float* x        = (const float*)d_in[0];
  const float* h        = (const float*)d_in[1];
  const float* c        = (const float*)d_in[2];
  const int*   children = (const int*)d_in[3];
  const int*   is_leaf  = (const int*)d_in[4];
  const float* W_iou    = (const float*)d_in[5];
  const float* b_Wiou   = (const float*)d_in[6];
  const float* U_iou    = (const float*)d_in[7];
  const float* b_Uiou   = (const float*)d_in[8];
  const float* U_f      = (const float*)d_in[9];
  const float* b_Uf     = (const float*)d_in[10];

  const int N = in_sizes[3] / 2;       // children is [N,2]
  const int grid = (N + 63) / 64;
  treelstm<<<grid, 256, 0, stream>>>(x, h, c, children, is_leaf,
                                     W_iou, b_Wiou, U_iou, b_Uiou, U_f, b_Uf,
                                     (float*)d_out, N);
}